// Round 4
// baseline (248.253 us; speedup 1.0000x reference)
//
#include <hip/hip_runtime.h>
#include <math.h>

constexpr int Bc = 32;     // batch
constexpr int Tc = 1000;   // time
constexpr int Vc = 1024;   // vocab
constexpr int Lc = 128;    // label length
constexpr int Sc = 2 * Lc + 1;  // 257 lattice states
constexpr int SP = 320;         // padded stride (positions 0..319)
constexpr float NEGF = -1e30f;
constexpr float L2E = 1.4426950408889634f;   // log2(e)
constexpr float LN2 = 0.6931471805599453f;   // ln(2)
constexpr int ENEG = -(1 << 24);             // sentinel exponent: "no mass"

#if __has_builtin(__builtin_amdgcn_exp2f)
#define EXP2F(x) __builtin_amdgcn_exp2f(x)
#else
#define EXP2F(x) exp2f(x)
#endif
#if __has_builtin(__builtin_amdgcn_logf)
#define LOG2F(x) __builtin_amdgcn_logf(x)
#else
#define LOG2F(x) log2f(x)
#endif
#if __has_builtin(__builtin_amdgcn_ldexpf)
#define LDEXPF(x, e) __builtin_amdgcn_ldexpf(x, e)
#else
#define LDEXPF(x, e) ldexpf(x, e)
#endif
#if __has_builtin(__builtin_amdgcn_frexp_expf)
#define FREXPE(x) __builtin_amdgcn_frexp_expf(x)
#else
__device__ inline int FREXPE(float x) { int e; (void)frexpf(x, &e); return e; }
#endif

// DPP wave_shr:1 — lane l receives lane l-1's value; lane 0 gets 0
// (bound_ctrl=1). VALU-latency cross-lane move, replaces ds_bpermute shfl_up.
__device__ __forceinline__ float dpp_wave_shr1(float x) {
  return __int_as_float(__builtin_amdgcn_update_dpp(
      0, __float_as_int(x), 0x138 /* wave_shr:1 */, 0xf, 0xf, true));
}
__device__ __forceinline__ int dpp_wave_shr1_i(int x) {
  return __builtin_amdgcn_update_dpp(0, x, 0x138 /* wave_shr:1 */, 0xf, 0xf, true);
}

// Parity-uniform layout: lane l holds states s = 4l+j (slots j=0..3), plus
// state 256 in slot 4 of lane 63. Position: p = j*64 + lane (j<4), 256+lane
// (slot 4). Slots 0,2,4 = blanks; 1,3 = labels. One cross-lane value per
// step: state 4l-1 = lane l-1 slot 3. Values are LINEAR probabilities.

// ---------------------------------------------------------------------------
// Kernel A: log-softmax + gather, one WAVE per (b,t) row; stores LINEAR
// p = exp2(x - lse). Padding slots store 0. (Unchanged — control.)
// ---------------------------------------------------------------------------
__global__ __launch_bounds__(256) void ctc_lse_gather(
    const float* __restrict__ hs, const int* __restrict__ ys,
    float* __restrict__ lpe) {
  const int wv = threadIdx.x >> 6;
  const int lane = threadIdx.x & 63;
  const int bt = blockIdx.x * 4 + wv;   // row index b*Tc + t
  const int b = bt / Tc;
  const float* row = hs + (size_t)bt * Vc;

  __shared__ float xs_all[4][Vc];
  float* xs = xs_all[wv];

  float4 v[4];
#pragma unroll
  for (int q = 0; q < 4; ++q) v[q] = reinterpret_cast<const float4*>(row)[lane + 64 * q];
#pragma unroll
  for (int q = 0; q < 4; ++q) { v[q].x *= L2E; v[q].y *= L2E; v[q].z *= L2E; v[q].w *= L2E; }

  float m = -3.4e38f;
#pragma unroll
  for (int q = 0; q < 4; ++q)
    m = fmaxf(m, fmaxf(fmaxf(v[q].x, v[q].y), fmaxf(v[q].z, v[q].w)));
#pragma unroll
  for (int off = 32; off; off >>= 1) m = fmaxf(m, __shfl_xor(m, off, 64));

  float sum = 0.f;
#pragma unroll
  for (int q = 0; q < 4; ++q)
    sum += EXP2F(v[q].x - m) + EXP2F(v[q].y - m) + EXP2F(v[q].z - m) + EXP2F(v[q].w - m);
#pragma unroll
  for (int off = 32; off; off >>= 1) sum += __shfl_xor(sum, off, 64);
  const float lse2 = m + LOG2F(sum);

#pragma unroll
  for (int q = 0; q < 4; ++q) reinterpret_cast<float4*>(xs)[lane + 64 * q] = v[q];
  __syncthreads();

  float* out = lpe + (size_t)bt * SP;
#pragma unroll
  for (int j = 0; j < 4; ++j) {     // states s = 4*lane + j (0..255)
    const int s = 4 * lane + j;
    const int lab = (s & 1) ? ys[b * Lc + (s >> 1)] : 0;
    out[j * 64 + lane] = EXP2F(xs[lab] - lse2);   // linear prob
  }
  // slot 4: state 256 (last blank) on lane 63, 0 elsewhere
  out[256 + lane] = (lane == 63) ? EXP2F(xs[0] - lse2) : 0.f;
}

// ---------------------------------------------------------------------------
// Kernel B: CTC alpha, LINEAR domain with per-lane integer exponent that is
// reconciled only once per 8-step GROUP (linear probs decay <~2^-15/step
// worst-case for this data, so 8 steps stay far above the 2^-149 fp32 floor
// when the lane max starts in [0.5,1)). Within a group the per-step body is
// pure add/fma/mul plus ONE DPP cross-lane move: no frexp/ldexp/reconcile on
// the serial path.
// ---------------------------------------------------------------------------
__global__ __launch_bounds__(64) void ctc_alpha(
    const float* __restrict__ lpe, const int* __restrict__ ys,
    const int* __restrict__ hlen, const int* __restrict__ ylen,
    float* __restrict__ lossb) {
  const int b = blockIdx.x;
  const int lane = threadIdx.x;
  const float* pb = lpe + (size_t)b * Tc * SP;
  const int* yb = ys + b * Lc;

  // skip factors (wave-uniform slot parity): slot1: s=4l+1 (needs l>=1);
  // slot3: s=4l+3.
  const float sk1 = (lane >= 1 && yb[2 * lane - 1] != yb[2 * lane]) ? 1.f : 0.f;
  const float sk3 = (yb[2 * lane] != yb[2 * lane + 1]) ? 1.f : 0.f;

  // t=0: state 0 (lane0 slot0), state 1 (lane0 slot1); linear probs
  float m0 = (lane == 0) ? pb[0] : 0.f;
  float m1 = (lane == 0) ? pb[64] : 0.f;
  float m2 = 0.f, m3 = 0.f, m4 = 0.f;
  int E = (lane == 0) ? 0 : ENEG;     // sentinel: no mass on this lane yet
  float fsh = 0.f;                    // neighbor-scale factor, set by renorm()

  const int Te = min(hlen[b], Tc);

  // Group renorm: normalize lane max to [0.5,1), publish new exponent E1 to
  // the downstream lane, adopt scale En = max(E1, Eup) so the incoming
  // neighbor mantissa needs only a fixed multiplier fsh = 2^(Eup-En) <= 1.
  // All sentinel cases collapse to ldexp underflow -> 0 (no branches).
  auto renorm = [&]() {
    const float mx = fmaxf(fmaxf(fmaxf(m0, m1), fmaxf(m2, m3)), m4);
    const int e = FREXPE(mx);                 // mx = mant * 2^e, mant in [0.5,1)
    const int E1 = (mx > 0.f) ? E + e : ENEG; // true exponent of lane max
    int Eup = dpp_wave_shr1_i(E1);            // lane 0 gets 0 from bound_ctrl...
    if (lane == 0) Eup = ENEG;                // ...remap to the empty sentinel
    const int En = max(E1, Eup);              // working scale for next group
    const int dm = E - En;                    // rescale my mantissas to En
    fsh = LDEXPF(1.f, Eup - En);              // <=1; 0 if neighbor empty
    m0 = LDEXPF(m0, dm);
    m1 = LDEXPF(m1, dm);
    m2 = LDEXPF(m2, dm);
    m3 = LDEXPF(m3, dm);
    m4 = LDEXPF(m4, dm);
    E = En;
  };

  // Per-step body: 13 VALU ops, one DPP on the cross-lane path.
  auto step = [&](const float* p) {
    const float msh = dpp_wave_shr1(m3);   // state 4l-1 from lane l-1 (0 on lane 0)
    const float am = msh * fsh;            // at my scale
    const float n0 = (m0 + am) * p[0];                 // blank
    const float n1 = fmaf(sk1, am, m1 + m0) * p[1];    // label
    const float n2 = (m2 + m1) * p[2];                 // blank
    const float n3 = fmaf(sk3, m1, m3 + m2) * p[3];    // label
    const float n4 = (m4 + m3) * p[4];                 // last blank
    m0 = n0; m1 = n1; m2 = n2; m3 = n3; m4 = n4;
  };

  float bufA[8][5], bufB[8][5];
  auto load8A = [&](int trow) {
    const float* p = pb + (size_t)trow * SP + lane;
#pragma unroll
    for (int k = 0; k < 8; ++k)
#pragma unroll
      for (int j = 0; j < 5; ++j) bufA[k][j] = p[k * SP + j * 64];
  };
  auto load8B = [&](int trow) {
    const float* p = pb + (size_t)trow * SP + lane;
#pragma unroll
    for (int k = 0; k < 8; ++k)
#pragma unroll
      for (int j = 0; j < 5; ++j) bufB[k][j] = p[k * SP + j * 64];
  };

  int t = 1;
  if (t + 8 <= Te) load8A(t);
  while (t + 16 <= Te) {
    load8B(t + 8);
    renorm();
#pragma unroll
    for (int k = 0; k < 8; ++k) step(bufA[k]);
    t += 8;
    if (t + 16 <= Te) load8A(t + 8);
    renorm();
#pragma unroll
    for (int k = 0; k < 8; ++k) step(bufB[k]);
    t += 8;
  }
  if (t + 8 <= Te) {
    renorm();
#pragma unroll
    for (int k = 0; k < 8; ++k) step(bufA[k]);
    t += 8;
  }
  while (t < Te) {
    float lp[5];
#pragma unroll
    for (int j = 0; j < 5; ++j) lp[j] = pb[(size_t)t * SP + j * 64 + lane];
    renorm();
    step(lp);
    ++t;
  }

  // final: loss = -ln2 * log2(alpha[2L] + alpha[2L-1]) / ylen, scales exact
  __shared__ float msm[SP];
  __shared__ int esm[64];
#pragma unroll
  for (int j = 0; j < 4; ++j) msm[4 * lane + j] = (j == 0 ? m0 : j == 1 ? m1 : j == 2 ? m2 : m3);
  if (lane == 63) msm[256] = m4;
  esm[lane] = E;
  __syncthreads();
  if (lane == 0) {
    const int yl = ylen[b];
    const int s1 = 2 * yl, s0 = 2 * yl - 1;
    const int l1 = (s1 == 256) ? 63 : (s1 >> 2);
    const int l0 = s0 >> 2;
    const float vx = msm[s1]; const int ex = esm[l1];
    const float vy = msm[s0]; const int ey = esm[l0];
    const int Em = max(ex, ey);
    const float r = LDEXPF(vx, ex - Em) + LDEXPF(vy, ey - Em);
    const float ae2 = (r > 0.f) ? (LOG2F(r) + (float)Em) : NEGF;
    lossb[b] = -(ae2 * LN2) / (float)yl;
  }
}

// ---------------------------------------------------------------------------
// Kernel C: mean over batch
// ---------------------------------------------------------------------------
__global__ __launch_bounds__(64) void ctc_final(
    const float* __restrict__ lossb, float* __restrict__ out) {
  const int lane = threadIdx.x;
  float v = (lane < Bc) ? lossb[lane] : 0.f;
#pragma unroll
  for (int off = 32; off; off >>= 1) v += __shfl_xor(v, off, 64);
  if (lane == 0) out[0] = v * (1.f / (float)Bc);
}

extern "C" void kernel_launch(void* const* d_in, const int* in_sizes, int n_in,
                              void* d_out, int out_size, void* d_ws, size_t ws_size,
                              hipStream_t stream) {
  const float* hs = (const float*)d_in[0];    // (B,T,V) fp32
  const int* hlen = (const int*)d_in[1];      // (B,)
  const int* ys = (const int*)d_in[2];        // (B,L)
  const int* ylen = (const int*)d_in[3];      // (B,)
  float* out = (float*)d_out;                 // scalar

  float* lpe = (float*)d_ws;                             // B*T*SP floats (~41 MB)
  float* lossb = lpe + (size_t)Bc * Tc * SP;             // B floats

  ctc_lse_gather<<<Bc * Tc / 4, 256, 0, stream>>>(hs, ys, lpe);
  ctc_alpha<<<Bc, 64, 0, stream>>>(lpe, ys, hlen, ylen, lossb);
  ctc_final<<<1, 64, 0, stream>>>(lossb, out);
}